// Round 2
// baseline (332.641 us; speedup 1.0000x reference)
//
#include <hip/hip_runtime.h>
#include <hip/hip_bf16.h>

#define T_LEN 4096
#define BATCH 8
#define D_DIM 256
#define P_DIM 256
#define O_DIM 256
#define N3    768

typedef __bf16 bf16;
typedef __attribute__((ext_vector_type(8))) __bf16 bf16x8;
typedef __attribute__((ext_vector_type(4))) __bf16 bf16x4;
typedef __attribute__((ext_vector_type(4))) float f32x4;
typedef __attribute__((ext_vector_type(16))) float f32x16;

#define MFMA16(a, b, c) __builtin_amdgcn_mfma_f32_16x16x32_bf16(a, b, c, 0, 0, 0)
#define MFMA32(a, b, c) __builtin_amdgcn_mfma_f32_32x32x16_bf16(a, b, c, 0, 0, 0)

#define LDS_P 72  // P rows: 144B stride

// lgkm-only barrier: drains LDS (Ps visibility) but leaves global loads in
// flight across the barrier — the compiler's __syncthreads would emit
// s_waitcnt vmcnt(0) and kill the cross-iter prefetch pipeline.
#define BARRIER_LGKM() __asm__ __volatile__("s_waitcnt lgkmcnt(0)\n\ts_barrier" ::: "memory")

// ---------------------------------------------------------------------------
// K0: fragment-major weight pack (proven R6/R7).
// ---------------------------------------------------------------------------
__global__ __launch_bounds__(256) void wpack_kernel(
    const float* __restrict__ src, bf16* __restrict__ dst, int ncols)
{
    const int g = blockIdx.x * 256 + threadIdx.x;
    const int lane = g & 63;
    const int idx = g >> 6;
    const int nt = idx & 3, kt = (idx >> 2) & 7, ch = idx >> 5;
    const int n = ch * 64 + nt * 16 + (lane & 15);
    const int kb = kt * 32 + (lane >> 4) * 8;
    bf16x8 pk;
    #pragma unroll
    for (int j = 0; j < 8; ++j) pk[j] = (bf16)src[(size_t)(kb + j) * ncols + n];
    *(bf16x8*)&dst[(size_t)g * 8] = pk;
}

// ---------------------------------------------------------------------------
// K1 v4: qkv proj -> qb (plain), kpk/vpk (fragment-packed). Proven R7.
// ---------------------------------------------------------------------------
__global__ __launch_bounds__(256) void qkv_proj_kernel(
    const float* __restrict__ query, const bf16* __restrict__ wkp,
    const float* __restrict__ b_kqv,
    bf16* __restrict__ qb, bf16* __restrict__ kpk, bf16* __restrict__ vpk)
{
    __shared__ __align__(16) bf16 Vt[64][68];
    const int m0 = blockIdx.x * 64;
    const int tid = threadIdx.x;
    const int lane = tid & 63, wave = tid >> 6, l15 = lane & 15, quad = lane >> 4;
    const int arow = wave * 16 + l15;

    bf16x8 af[8];
    {
        const float* qsrc = query + (size_t)(m0 + arow) * D_DIM + quad * 8;
        #pragma unroll
        for (int kt = 0; kt < 8; ++kt) {
            float4 f0 = *(const float4*)(qsrc + kt * 32);
            float4 f1 = *(const float4*)(qsrc + kt * 32 + 4);
            af[kt] = bf16x8{(bf16)f0.x, (bf16)f0.y, (bf16)f0.z, (bf16)f0.w,
                            (bf16)f1.x, (bf16)f1.y, (bf16)f1.z, (bf16)f1.w};
        }
    }

    for (int ch = 0; ch < 12; ++ch) {
        f32x4 acc[4];
        #pragma unroll
        for (int i = 0; i < 4; ++i)
            for (int r = 0; r < 4; ++r) acc[i][r] = 0.f;
        #pragma unroll
        for (int kt = 0; kt < 8; ++kt) {
            #pragma unroll
            for (int nt = 0; nt < 4; ++nt) {
                bf16x8 bb = *(const bf16x8*)&wkp[((((size_t)ch * 8 + kt) * 4 + nt) * 64 + lane) * 8];
                acc[nt] = MFMA16(af[kt], bb, acc[nt]);
            }
        }
        if (ch < 4) {
            #pragma unroll
            for (int nt = 0; nt < 4; ++nt) {
                const int c = ch * 64 + nt * 16 + l15;
                const float bias = b_kqv[c];
                #pragma unroll
                for (int r = 0; r < 4; ++r) {
                    const int m = m0 + wave * 16 + quad * 4 + r;
                    const int t = m >> 3, bi = m & 7;
                    qb[((size_t)bi * T_LEN + t) * P_DIM + c] = (bf16)((acc[nt][r] + bias) * 0.0625f);
                }
            }
        } else if (ch < 8) {
            #pragma unroll
            for (int nt = 0; nt < 4; ++nt) {
                const int c = ch * 64 + nt * 16 + l15;
                const float bias = b_kqv[c];
                const int kk = c - 256;
                const int c16 = kk >> 4, halfk = (kk >> 3) & 1, j = kk & 7;
                #pragma unroll
                for (int r = 0; r < 4; ++r) {
                    const int m = m0 + wave * 16 + quad * 4 + r;
                    const int t = m >> 3, bi = m & 7;
                    const int st32 = t >> 5, n31 = t & 31;
                    kpk[((((size_t)bi * 128 + st32) * 16 + c16) * 64 + halfk * 32 + n31) * 8 + j]
                        = (bf16)(acc[nt][r] + bias);
                }
            }
        } else {
            __syncthreads();
            #pragma unroll
            for (int nt = 0; nt < 4; ++nt) {
                const int c = ch * 64 + nt * 16 + l15;
                const float bias = b_kqv[c];
                #pragma unroll
                for (int r = 0; r < 4; ++r)
                    Vt[nt * 16 + l15][wave * 16 + quad * 4 + r] = (bf16)(acc[nt][r] + bias);
            }
            __syncthreads();
            const int t0g = m0 >> 3;
            const int s64 = t0g >> 6, ks = (t0g >> 4) & 3, halfv = (t0g >> 3) & 1;
            #pragma unroll
            for (int uu = 0; uu < 2; ++uu) {
                const int u = tid * 2 + uu;
                const int cl = u >> 3, bi = u & 7;
                bf16x8 pk;
                #pragma unroll
                for (int j = 0; j < 8; ++j) pk[j] = Vt[cl][j * 8 + bi];
                const int cc = (ch - 8) * 64 + cl;
                const int ptG = cc >> 5, n31 = cc & 31;
                *(bf16x8*)&vpk[((((size_t)bi * 64 + s64) * 4 + ks) * 8 + ptG) * 512
                               + (size_t)(halfv * 32 + n31) * 8] = pk;
            }
        }
    }
}

// ---------------------------------------------------------------------------
// K2 v5: flash attention, PV pipelined one iter behind QK — register-neutral.
//  - Single bv buffer: V(i) loaded mid-iter i (after PV(i-1) consumed the old
//    values), consumed mid-iter i+1. No ping-pong, no spill (R1 post-mortem:
//    bvA/bvB +32 VGPR cross-barrier live range -> scratch, +2MB WRITE_SIZE).
//  - QK(i)+PV(i-1) form one contiguous 32-MFMA region wrapped in setprio(1):
//    the 2 blocks/CU are phase-independent; prio favors whichever block is in
//    its MFMA region while the other runs exp/loads at prio 0 (T5 regime).
//  - lgkm-only s_barrier: global loads stay in flight across it.
//  - Hazards: PV(i-1) reads Ps[buf^1] (written iter i-1, fenced by its
//    barrier); next write of that buffer is iter i+1, after this iter's
//    barrier which drains the reads via lgkmcnt(0).
// ---------------------------------------------------------------------------
__global__ __launch_bounds__(256, 2) void flash_attn_kernel(
    const bf16* __restrict__ qb, const bf16* __restrict__ kpk,
    const bf16* __restrict__ vpk, bf16* __restrict__ attn)
{
    __shared__ __align__(16) bf16 Ps[2][64][LDS_P];   // 18.4 KB
    __shared__ float l_red[2][64];                    // [sh][row]

    const int bid = blockIdx.x;
    const int b = bid & 7;                 // bid%8 == XCD: 4 MB KV per XCD L2
    const int t0 = (bid >> 3) * 64;
    const int tid = threadIdx.x;
    const int lane = tid & 63, wave = tid >> 6;
    const int l31 = lane & 31, half = lane >> 5;
    const int rg = wave & 1, sh = wave >> 1;

    // Q A-frags (row=lane&31, k=half*8+j), rows rg*32..+32 — proven layout
    bf16x8 qf[16];
    {
        const bf16* qrow = qb + ((size_t)b * T_LEN + t0 + rg * 32 + l31) * P_DIM + half * 8;
        #pragma unroll
        for (int kt = 0; kt < 16; ++kt) qf[kt] = *(const bf16x8*)(qrow + kt * 16);
    }

    f32x16 acc_o[2][2];   // [t-tile][p-tile]
    float l_part[16];
    #pragma unroll
    for (int i = 0; i < 16; ++i) {
        acc_o[0][0][i] = 0.f; acc_o[0][1][i] = 0.f;
        acc_o[1][0][i] = 0.f; acc_o[1][1][i] = 0.f;
        l_part[i] = 0.f;
    }

    const bf16* kfb = kpk + (size_t)b * 128 * 16 * 512;
    const bf16* vfb = vpk + (size_t)b * 64 * 4 * 8 * 512;

    // prime the K prefetch for s0 = 0
    bf16x8 kpre[8];
    {
        const bf16* kf0 = kfb + ((size_t)sh * 16 * 64 + lane) * 8;
        #pragma unroll
        for (int c = 0; c < 8; ++c) kpre[c] = *(const bf16x8*)(kf0 + (size_t)c * 512);
    }

    bf16x8 bv[8];   // V(i) loaded mid-iter i, consumed by PV(i) in iter i+1

/* One s0-step: kc2 load -> [prio1] QK(S0) + PV(S0-64) [prio0] -> kpre(S0+64)
   load -> bv=V(S0) load -> exp/Ps[buf] store -> lgkm barrier.              */
#define FA_ITER(S0, DO_PV)                                                    \
{                                                                             \
    const int buf = ((S0) >> 6) & 1;                                          \
    const bf16* kf  = kfb + (((size_t)(((S0) >> 5) + sh)) * 16 * 64 + lane) * 8;        \
    const bf16* kfn = kfb + (((size_t)((((S0) + 64) >> 5) + sh)) * 16 * 64 + lane) * 8; \
    bf16x8 kc2[8];                                                            \
    _Pragma("unroll")                                                         \
    for (int c = 0; c < 8; ++c) kc2[c] = *(const bf16x8*)(kf + (size_t)(8 + c) * 512);  \
    f32x16 accs;                                                              \
    _Pragma("unroll")                                                         \
    for (int i = 0; i < 16; ++i) accs[i] = 0.f;                               \
    __builtin_amdgcn_s_setprio(1);                                            \
    _Pragma("unroll")                                                         \
    for (int c = 0; c < 8; ++c) accs = MFMA32(qf[c], kpre[c], accs);          \
    _Pragma("unroll")                                                         \
    for (int c = 0; c < 8; ++c) accs = MFMA32(qf[8 + c], kc2[c], accs);       \
    if (DO_PV) {                                                              \
        const int pbuf = buf ^ 1;                                             \
        _Pragma("unroll")                                                     \
        for (int ks = 0; ks < 4; ++ks) {                                      \
            bf16x8 ap0 = *(const bf16x8*)&Ps[pbuf][l31][ks * 16 + half * 8];  \
            bf16x8 ap1 = *(const bf16x8*)&Ps[pbuf][32 + l31][ks * 16 + half * 8];       \
            acc_o[0][0] = MFMA32(ap0, bv[ks * 2],     acc_o[0][0]);           \
            acc_o[0][1] = MFMA32(ap0, bv[ks * 2 + 1], acc_o[0][1]);           \
            acc_o[1][0] = MFMA32(ap1, bv[ks * 2],     acc_o[1][0]);           \
            acc_o[1][1] = MFMA32(ap1, bv[ks * 2 + 1], acc_o[1][1]);           \
        }                                                                     \
    }                                                                         \
    __builtin_amdgcn_s_setprio(0);                                            \
    _Pragma("unroll")                                                         \
    for (int c = 0; c < 8; ++c) kpre[c] = *(const bf16x8*)(kfn + (size_t)c * 512);      \
    const bf16* vf = vfb + (((size_t)((S0) >> 6) * 4) * 8 + wave * 2) * 512 + (size_t)lane * 8; \
    _Pragma("unroll")                                                         \
    for (int ks = 0; ks < 4; ++ks) {                                          \
        bv[ks * 2]     = *(const bf16x8*)(vf + (size_t)ks * 8 * 512);         \
        bv[ks * 2 + 1] = *(const bf16x8*)(vf + (size_t)(ks * 8 + 1) * 512);   \
    }                                                                         \
    _Pragma("unroll")                                                         \
    for (int r = 0; r < 16; ++r) {                                            \
        float p = __expf(accs[r]);                                            \
        bf16 pb = (bf16)p;                                                    \
        l_part[r] += (float)pb;                                               \
        int row = rg * 32 + (r & 3) + 8 * (r >> 2) + 4 * half;                \
        Ps[buf][row][sh * 32 + l31] = pb;                                     \
    }                                                                         \
    BARRIER_LGKM();                                                           \
}

    // iter 0 peeled: no PV yet; loads bv = V(0)
    FA_ITER(0, 0)

    for (int s0 = 64; s0 < T_LEN; s0 += 64) {
        FA_ITER(s0, 1)
    }

    // drain: PV(63) — Ps[1] written iter 63 (visible after its barrier),
    // bv = V(63) loaded iter 63.
    {
        #pragma unroll
        for (int ks = 0; ks < 4; ++ks) {
            bf16x8 ap0 = *(const bf16x8*)&Ps[1][l31][ks * 16 + half * 8];
            bf16x8 ap1 = *(const bf16x8*)&Ps[1][32 + l31][ks * 16 + half * 8];
            acc_o[0][0] = MFMA32(ap0, bv[ks * 2],     acc_o[0][0]);
            acc_o[0][1] = MFMA32(ap0, bv[ks * 2 + 1], acc_o[0][1]);
            acc_o[1][0] = MFMA32(ap1, bv[ks * 2],     acc_o[1][0]);
            acc_o[1][1] = MFMA32(ap1, bv[ks * 2 + 1], acc_o[1][1]);
        }
    }
#undef FA_ITER

    // ---- l reduction: across 32 cols (shuffle), then across sh waves (LDS) ----
    #pragma unroll
    for (int r = 0; r < 16; ++r) {
        float v = l_part[r];
        v += __shfl_xor(v, 1, 64);
        v += __shfl_xor(v, 2, 64);
        v += __shfl_xor(v, 4, 64);
        v += __shfl_xor(v, 8, 64);
        v += __shfl_xor(v, 16, 64);
        l_part[r] = v;
    }
    if (l31 == 0) {
        #pragma unroll
        for (int r = 0; r < 16; ++r) {
            const int row = rg * 32 + (r & 3) + 8 * (r >> 2) + 4 * half;
            l_red[sh][row] = l_part[r];
        }
    }
    __syncthreads();

    // epilogue: attn[(t*B+b)*P + p] = O / (l0+l1)
    #pragma unroll
    for (int rt = 0; rt < 2; ++rt) {
        #pragma unroll
        for (int r = 0; r < 16; ++r) {
            const int row = rt * 32 + (r & 3) + 8 * (r >> 2) + 4 * half;
            const float linv = 1.0f / (l_red[0][row] + l_red[1][row]);
            bf16* dst = attn + ((size_t)(t0 + row) * BATCH + b) * P_DIM + wave * 64 + l31;
            dst[0]  = (bf16)(acc_o[rt][0][r] * linv);
            dst[32] = (bf16)(acc_o[rt][1][r] * linv);
        }
    }
}

// ---------------------------------------------------------------------------
// K3 v3: out = attn @ W_out + b_out. LDS-free, packed B-frags (proven).
// ---------------------------------------------------------------------------
__global__ __launch_bounds__(256) void out_proj_kernel(
    const bf16* __restrict__ attn, const bf16* __restrict__ wop,
    const float* __restrict__ b_out, float* __restrict__ out)
{
    const int m0 = blockIdx.x * 64;
    const int tid = threadIdx.x;
    const int lane = tid & 63, wave = tid >> 6, l15 = lane & 15, quad = lane >> 4;
    const int arow = wave * 16 + l15;

    bf16x8 af[8];
    {
        const bf16* asrc = attn + (size_t)(m0 + arow) * P_DIM + quad * 8;
        #pragma unroll
        for (int kt = 0; kt < 8; ++kt) af[kt] = *(const bf16x8*)(asrc + kt * 32);
    }

    for (int ch = 0; ch < 4; ++ch) {
        f32x4 acc[4];
        #pragma unroll
        for (int i = 0; i < 4; ++i)
            for (int r = 0; r < 4; ++r) acc[i][r] = 0.f;
        #pragma unroll
        for (int kt = 0; kt < 8; ++kt) {
            #pragma unroll
            for (int nt = 0; nt < 4; ++nt) {
                bf16x8 bb = *(const bf16x8*)&wop[((((size_t)ch * 8 + kt) * 4 + nt) * 64 + lane) * 8];
                acc[nt] = MFMA16(af[kt], bb, acc[nt]);
            }
        }
        #pragma unroll
        for (int nt = 0; nt < 4; ++nt) {
            const int n = ch * 64 + nt * 16 + l15;
            const float bias = b_out[n];
            #pragma unroll
            for (int r = 0; r < 4; ++r) {
                const int m = m0 + wave * 16 + quad * 4 + r;
                out[(size_t)m * O_DIM + n] = acc[nt][r] + bias;
            }
        }
    }
}

extern "C" void kernel_launch(void* const* d_in, const int* in_sizes, int n_in,
                              void* d_out, int out_size, void* d_ws, size_t ws_size,
                              hipStream_t stream) {
    const float* query = (const float*)d_in[0];
    const float* W_kqv = (const float*)d_in[1];
    const float* b_kqv = (const float*)d_in[2];
    const float* W_out = (const float*)d_in[3];
    const float* b_out = (const float*)d_in[4];
    float* out = (float*)d_out;

    const size_t BUF = (size_t)BATCH * T_LEN * P_DIM;
    bf16* qb   = (bf16*)d_ws;
    bf16* kpk  = qb + BUF;     // fragment-packed K
    bf16* vpk  = kpk + BUF;    // fragment-packed V
    bf16* attn = vpk + BUF;    // [T][B][P]
    bf16* wkp = attn;          // overlay: dead until K2 writes attn
    bf16* wop = qb;            // overlay: packed after K2 consumed qb

    wpack_kernel<<<96, 256, 0, stream>>>(W_kqv, wkp, N3);
    qkv_proj_kernel<<<512, 256, 0, stream>>>(query, wkp, b_kqv, qb, kpk, vpk);
    flash_attn_kernel<<<512, 256, 0, stream>>>(qb, kpk, vpk, attn);
    wpack_kernel<<<32, 256, 0, stream>>>(W_out, wop, O_DIM);
    out_proj_kernel<<<512, 256, 0, stream>>>(attn, wop, b_out, out);
}

// Round 3
// 303.416 us; speedup vs baseline: 1.0963x; 1.0963x over previous
//
#include <hip/hip_runtime.h>
#include <hip/hip_bf16.h>

#define T_LEN 4096
#define BATCH 8
#define D_DIM 256
#define P_DIM 256
#define O_DIM 256
#define N3    768

typedef __bf16 bf16;
typedef __attribute__((ext_vector_type(8))) __bf16 bf16x8;
typedef __attribute__((ext_vector_type(4))) __bf16 bf16x4;
typedef __attribute__((ext_vector_type(4))) float f32x4;
typedef __attribute__((ext_vector_type(16))) float f32x16;

#define MFMA16(a, b, c) __builtin_amdgcn_mfma_f32_16x16x32_bf16(a, b, c, 0, 0, 0)
#define MFMA32(a, b, c) __builtin_amdgcn_mfma_f32_32x32x16_bf16(a, b, c, 0, 0, 0)

#define LDS_P 72  // P rows: 144B stride (proven conflict-free with ds_read_b128)

// lgkm-only barrier: drains LDS (Ps visibility) but leaves global loads in
// flight across the barrier — the compiler's __syncthreads would emit
// s_waitcnt vmcnt(0) and kill the cross-iter prefetch pipeline.
#define BARRIER_LGKM() __asm__ __volatile__("s_waitcnt lgkmcnt(0)\n\ts_barrier" ::: "memory")

// ---------------------------------------------------------------------------
// K0: fragment-major weight pack (proven R6/R7).
// ---------------------------------------------------------------------------
__global__ __launch_bounds__(256) void wpack_kernel(
    const float* __restrict__ src, bf16* __restrict__ dst, int ncols)
{
    const int g = blockIdx.x * 256 + threadIdx.x;
    const int lane = g & 63;
    const int idx = g >> 6;
    const int nt = idx & 3, kt = (idx >> 2) & 7, ch = idx >> 5;
    const int n = ch * 64 + nt * 16 + (lane & 15);
    const int kb = kt * 32 + (lane >> 4) * 8;
    bf16x8 pk;
    #pragma unroll
    for (int j = 0; j < 8; ++j) pk[j] = (bf16)src[(size_t)(kb + j) * ncols + n];
    *(bf16x8*)&dst[(size_t)g * 8] = pk;
}

// ---------------------------------------------------------------------------
// K1 v4: qkv proj -> qb (plain), kpk/vpk (fragment-packed). Proven R7.
// ---------------------------------------------------------------------------
__global__ __launch_bounds__(256) void qkv_proj_kernel(
    const float* __restrict__ query, const bf16* __restrict__ wkp,
    const float* __restrict__ b_kqv,
    bf16* __restrict__ qb, bf16* __restrict__ kpk, bf16* __restrict__ vpk)
{
    __shared__ __align__(16) bf16 Vt[64][68];
    const int m0 = blockIdx.x * 64;
    const int tid = threadIdx.x;
    const int lane = tid & 63, wave = tid >> 6, l15 = lane & 15, quad = lane >> 4;
    const int arow = wave * 16 + l15;

    bf16x8 af[8];
    {
        const float* qsrc = query + (size_t)(m0 + arow) * D_DIM + quad * 8;
        #pragma unroll
        for (int kt = 0; kt < 8; ++kt) {
            float4 f0 = *(const float4*)(qsrc + kt * 32);
            float4 f1 = *(const float4*)(qsrc + kt * 32 + 4);
            af[kt] = bf16x8{(bf16)f0.x, (bf16)f0.y, (bf16)f0.z, (bf16)f0.w,
                            (bf16)f1.x, (bf16)f1.y, (bf16)f1.z, (bf16)f1.w};
        }
    }

    for (int ch = 0; ch < 12; ++ch) {
        f32x4 acc[4];
        #pragma unroll
        for (int i = 0; i < 4; ++i)
            for (int r = 0; r < 4; ++r) acc[i][r] = 0.f;
        #pragma unroll
        for (int kt = 0; kt < 8; ++kt) {
            #pragma unroll
            for (int nt = 0; nt < 4; ++nt) {
                bf16x8 bb = *(const bf16x8*)&wkp[((((size_t)ch * 8 + kt) * 4 + nt) * 64 + lane) * 8];
                acc[nt] = MFMA16(af[kt], bb, acc[nt]);
            }
        }
        if (ch < 4) {
            #pragma unroll
            for (int nt = 0; nt < 4; ++nt) {
                const int c = ch * 64 + nt * 16 + l15;
                const float bias = b_kqv[c];
                #pragma unroll
                for (int r = 0; r < 4; ++r) {
                    const int m = m0 + wave * 16 + quad * 4 + r;
                    const int t = m >> 3, bi = m & 7;
                    qb[((size_t)bi * T_LEN + t) * P_DIM + c] = (bf16)((acc[nt][r] + bias) * 0.0625f);
                }
            }
        } else if (ch < 8) {
            #pragma unroll
            for (int nt = 0; nt < 4; ++nt) {
                const int c = ch * 64 + nt * 16 + l15;
                const float bias = b_kqv[c];
                const int kk = c - 256;
                const int c16 = kk >> 4, halfk = (kk >> 3) & 1, j = kk & 7;
                #pragma unroll
                for (int r = 0; r < 4; ++r) {
                    const int m = m0 + wave * 16 + quad * 4 + r;
                    const int t = m >> 3, bi = m & 7;
                    const int st32 = t >> 5, n31 = t & 31;
                    kpk[((((size_t)bi * 128 + st32) * 16 + c16) * 64 + halfk * 32 + n31) * 8 + j]
                        = (bf16)(acc[nt][r] + bias);
                }
            }
        } else {
            __syncthreads();
            #pragma unroll
            for (int nt = 0; nt < 4; ++nt) {
                const int c = ch * 64 + nt * 16 + l15;
                const float bias = b_kqv[c];
                #pragma unroll
                for (int r = 0; r < 4; ++r)
                    Vt[nt * 16 + l15][wave * 16 + quad * 4 + r] = (bf16)(acc[nt][r] + bias);
            }
            __syncthreads();
            const int t0g = m0 >> 3;
            const int s64 = t0g >> 6, ks = (t0g >> 4) & 3, halfv = (t0g >> 3) & 1;
            #pragma unroll
            for (int uu = 0; uu < 2; ++uu) {
                const int u = tid * 2 + uu;
                const int cl = u >> 3, bi = u & 7;
                bf16x8 pk;
                #pragma unroll
                for (int j = 0; j < 8; ++j) pk[j] = Vt[cl][j * 8 + bi];
                const int cc = (ch - 8) * 64 + cl;
                const int ptG = cc >> 5, n31 = cc & 31;
                *(bf16x8*)&vpk[((((size_t)bi * 64 + s64) * 4 + ks) * 8 + ptG) * 512
                               + (size_t)(halfv * 32 + n31) * 8] = pk;
            }
        }
    }
}

// ---------------------------------------------------------------------------
// K2 v6: flash attention, 512-thread block, t-tile 128 (1 block/CU).
//  - R0's proven schedule per iter (kc2 ld -> QK -> bv ld -> kpre ld -> exp ->
//    lgkm barrier -> PV). No cross-iter V state: R1/R2 proved +32 VGPR across
//    the barrier forces spills at 4-wave geometry.
//  - Geometry change: 8 waves = 4 t-groups x 2 s-halves. Each K/V tile is read
//    ONCE per CU per iter (was twice: 2 blocks, same b, different t0) ->
//    halves L2 KV traffic; K-frags shared by 4 waves via L1 (was 2).
//  - bv shrinks 8->4 frags (wave owns one 32-col p-group for all 128 rows).
//  - 512-thread block @ 2 waves/SIMD -> 256-reg/wave budget: acc_o (64 AGPR)
//    + ~190 VGPR fits without the 128-VGPR cap that spilled R1/R2.
//  - WRITE_SIZE must stay exactly 16384 KB (attn) — spill tripwire.
// ---------------------------------------------------------------------------
__global__ __launch_bounds__(512, 2) void flash_attn_kernel(
    const bf16* __restrict__ qb, const bf16* __restrict__ kpk,
    const bf16* __restrict__ vpk, bf16* __restrict__ attn)
{
    __shared__ __align__(16) bf16 Ps[2][128][LDS_P];   // 36.9 KB
    __shared__ float l_red[2][128];                    // [sh][row]

    const int bid = blockIdx.x;
    const int b = bid & 7;                 // bid%8 == XCD: 4 MB KV per XCD L2
    const int t0 = (bid >> 3) * 128;
    const int tid = threadIdx.x;
    const int lane = tid & 63, wave = tid >> 6;        // wave 0..7
    const int l31 = lane & 31, half = lane >> 5;
    const int sh = wave & 1, tg = wave >> 1;           // s-half, t-group

    // Q A-frags (row=lane&31, k=half*8+j), rows tg*32..+32 — proven layout
    bf16x8 qf[16];
    {
        const bf16* qrow = qb + ((size_t)b * T_LEN + t0 + tg * 32 + l31) * P_DIM + half * 8;
        #pragma unroll
        for (int kt = 0; kt < 16; ++kt) qf[kt] = *(const bf16x8*)(qrow + kt * 16);
    }

    f32x16 acc_o[4];      // O rows rt*32.., cols wave*32..+32
    float l_part[16];
    #pragma unroll
    for (int i = 0; i < 16; ++i) {
        acc_o[0][i] = 0.f; acc_o[1][i] = 0.f;
        acc_o[2][i] = 0.f; acc_o[3][i] = 0.f;
        l_part[i] = 0.f;
    }

    const bf16* kfb = kpk + (size_t)b * 128 * 16 * 512;
    const bf16* vfb = vpk + (size_t)b * 64 * 4 * 8 * 512;

    // prime the K prefetch for s0 = 0 (st32 = sh)
    bf16x8 kpre[8];
    {
        const bf16* kf0 = kfb + ((size_t)sh * 16 * 64 + lane) * 8;
        #pragma unroll
        for (int c = 0; c < 8; ++c) kpre[c] = *(const bf16x8*)(kf0 + (size_t)c * 512);
    }

    for (int s0 = 0; s0 < T_LEN; s0 += 64) {
        const int buf = (s0 >> 6) & 1;
        const bf16* kf  = kfb + (((size_t)((s0 >> 5) + sh)) * 16 * 64 + lane) * 8;
        const bf16* kfn = kfb + (((size_t)(((s0 + 64) >> 5) + sh)) * 16 * 64 + lane) * 8;

        // second half of current iter's K-frags (c = 8..15)
        bf16x8 kc2[8];
        #pragma unroll
        for (int c = 0; c < 8; ++c) kc2[c] = *(const bf16x8*)(kf + (size_t)(8 + c) * 512);

        // QK: S quadrant [t=tg*32..+32][s=s0+sh*32..+32], K=256
        f32x16 accs;
        #pragma unroll
        for (int i = 0; i < 16; ++i) accs[i] = 0.f;
        #pragma unroll
        for (int c = 0; c < 8; ++c) accs = MFMA32(qf[c], kpre[c], accs);
        #pragma unroll
        for (int c = 0; c < 8; ++c) accs = MFMA32(qf[8 + c], kc2[c], accs);

        // V-frags for this iter's PV (post-barrier): ks=0..3, ptG = wave
        const bf16* vf = vfb + (((size_t)(s0 >> 6) * 4) * 8 + wave) * 512 + (size_t)lane * 8;
        bf16x8 bv[4];
        #pragma unroll
        for (int ks = 0; ks < 4; ++ks)
            bv[ks] = *(const bf16x8*)(vf + (size_t)ks * 8 * 512);

        // next-iter K prefetch — flies through exp/Ps/barrier
        #pragma unroll
        for (int c = 0; c < 8; ++c) kpre[c] = *(const bf16x8*)(kfn + (size_t)c * 512);

        // P = exp(S); l accumulated on the bf16-rounded value (matches numerator)
        #pragma unroll
        for (int r = 0; r < 16; ++r) {
            float p = __expf(accs[r]);
            bf16 pb = (bf16)p;
            l_part[r] += (float)pb;
            int row = tg * 32 + (r & 3) + 8 * (r >> 2) + 4 * half;
            Ps[buf][row][sh * 32 + l31] = pb;
        }

        BARRIER_LGKM();   // Ps[buf] visible; global loads stay outstanding

        // PV: O[0..127][wave*32..+32) += P @ V
        #pragma unroll
        for (int ks = 0; ks < 4; ++ks) {
            #pragma unroll
            for (int rt = 0; rt < 4; ++rt) {
                bf16x8 ap = *(const bf16x8*)&Ps[buf][rt * 32 + l31][ks * 16 + half * 8];
                acc_o[rt] = MFMA32(ap, bv[ks], acc_o[rt]);
            }
        }
    }

    // ---- l reduction: across 32 cols (shuffle), then across sh halves (LDS) ----
    #pragma unroll
    for (int r = 0; r < 16; ++r) {
        float v = l_part[r];
        v += __shfl_xor(v, 1, 64);
        v += __shfl_xor(v, 2, 64);
        v += __shfl_xor(v, 4, 64);
        v += __shfl_xor(v, 8, 64);
        v += __shfl_xor(v, 16, 64);
        l_part[r] = v;
    }
    if (l31 == 0) {
        #pragma unroll
        for (int r = 0; r < 16; ++r) {
            const int row = tg * 32 + (r & 3) + 8 * (r >> 2) + 4 * half;
            l_red[sh][row] = l_part[r];
        }
    }
    __syncthreads();

    // epilogue: attn[(t*B+b)*P + p] = O / (l0+l1), p = wave*32 + l31
    #pragma unroll
    for (int rt = 0; rt < 4; ++rt) {
        #pragma unroll
        for (int r = 0; r < 16; ++r) {
            const int row = rt * 32 + (r & 3) + 8 * (r >> 2) + 4 * half;
            const float linv = 1.0f / (l_red[0][row] + l_red[1][row]);
            attn[((size_t)(t0 + row) * BATCH + b) * P_DIM + wave * 32 + l31]
                = (bf16)(acc_o[rt][r] * linv);
        }
    }
}

// ---------------------------------------------------------------------------
// K3 v3: out = attn @ W_out + b_out. LDS-free, packed B-frags (proven).
// ---------------------------------------------------------------------------
__global__ __launch_bounds__(256) void out_proj_kernel(
    const bf16* __restrict__ attn, const bf16* __restrict__ wop,
    const float* __restrict__ b_out, float* __restrict__ out)
{
    const int m0 = blockIdx.x * 64;
    const int tid = threadIdx.x;
    const int lane = tid & 63, wave = tid >> 6, l15 = lane & 15, quad = lane >> 4;
    const int arow = wave * 16 + l15;

    bf16x8 af[8];
    {
        const bf16* asrc = attn + (size_t)(m0 + arow) * P_DIM + quad * 8;
        #pragma unroll
        for (int kt = 0; kt < 8; ++kt) af[kt] = *(const bf16x8*)(asrc + kt * 32);
    }

    for (int ch = 0; ch < 4; ++ch) {
        f32x4 acc[4];
        #pragma unroll
        for (int i = 0; i < 4; ++i)
            for (int r = 0; r < 4; ++r) acc[i][r] = 0.f;
        #pragma unroll
        for (int kt = 0; kt < 8; ++kt) {
            #pragma unroll
            for (int nt = 0; nt < 4; ++nt) {
                bf16x8 bb = *(const bf16x8*)&wop[((((size_t)ch * 8 + kt) * 4 + nt) * 64 + lane) * 8];
                acc[nt] = MFMA16(af[kt], bb, acc[nt]);
            }
        }
        #pragma unroll
        for (int nt = 0; nt < 4; ++nt) {
            const int n = ch * 64 + nt * 16 + l15;
            const float bias = b_out[n];
            #pragma unroll
            for (int r = 0; r < 4; ++r) {
                const int m = m0 + wave * 16 + quad * 4 + r;
                out[(size_t)m * O_DIM + n] = acc[nt][r] + bias;
            }
        }
    }
}

extern "C" void kernel_launch(void* const* d_in, const int* in_sizes, int n_in,
                              void* d_out, int out_size, void* d_ws, size_t ws_size,
                              hipStream_t stream) {
    const float* query = (const float*)d_in[0];
    const float* W_kqv = (const float*)d_in[1];
    const float* b_kqv = (const float*)d_in[2];
    const float* W_out = (const float*)d_in[3];
    const float* b_out = (const float*)d_in[4];
    float* out = (float*)d_out;

    const size_t BUF = (size_t)BATCH * T_LEN * P_DIM;
    bf16* qb   = (bf16*)d_ws;
    bf16* kpk  = qb + BUF;     // fragment-packed K
    bf16* vpk  = kpk + BUF;    // fragment-packed V
    bf16* attn = vpk + BUF;    // [T][B][P]
    bf16* wkp = attn;          // overlay: dead until K2 writes attn
    bf16* wop = qb;            // overlay: packed after K2 consumed qb

    wpack_kernel<<<96, 256, 0, stream>>>(W_kqv, wkp, N3);
    qkv_proj_kernel<<<512, 256, 0, stream>>>(query, wkp, b_kqv, qb, kpk, vpk);
    flash_attn_kernel<<<256, 512, 0, stream>>>(qb, kpk, vpk, attn);
    wpack_kernel<<<32, 256, 0, stream>>>(W_out, wop, O_DIM);
    out_proj_kernel<<<512, 256, 0, stream>>>(attn, wop, b_out, out);
}

// Round 4
// 275.901 us; speedup vs baseline: 1.2057x; 1.0997x over previous
//
#include <hip/hip_runtime.h>
#include <hip/hip_bf16.h>

#define T_LEN 4096
#define BATCH 8
#define D_DIM 256
#define P_DIM 256
#define O_DIM 256
#define N3    768

typedef __bf16 bf16;
typedef __attribute__((ext_vector_type(8))) __bf16 bf16x8;
typedef __attribute__((ext_vector_type(4))) __bf16 bf16x4;
typedef __attribute__((ext_vector_type(4))) float f32x4;
typedef __attribute__((ext_vector_type(16))) float f32x16;

#define MFMA16(a, b, c) __builtin_amdgcn_mfma_f32_16x16x32_bf16(a, b, c, 0, 0, 0)
#define MFMA32(a, b, c) __builtin_amdgcn_mfma_f32_32x32x16_bf16(a, b, c, 0, 0, 0)

#define LDS_P 72  // P rows: 144B stride

// lgkm-only barrier: drains LDS (Ps visibility) but leaves global loads in
// flight across the barrier — the compiler's __syncthreads would emit
// s_waitcnt vmcnt(0) and kill the cross-iter prefetch pipeline.
#define BARRIER_LGKM() __asm__ __volatile__("s_waitcnt lgkmcnt(0)\n\ts_barrier" ::: "memory")

// ---------------------------------------------------------------------------
// K0: fragment-major weight pack (proven R6/R7), both weights in ONE dispatch.
// Blocks 0..95 pack W_kqv (768 cols) -> wkp; blocks 96..127 pack W_out -> wop.
// ---------------------------------------------------------------------------
__device__ __forceinline__ void wpack_body(
    const float* __restrict__ src, bf16* __restrict__ dst, int ncols, int g)
{
    const int lane = g & 63;
    const int idx = g >> 6;
    const int nt = idx & 3, kt = (idx >> 2) & 7, ch = idx >> 5;
    const int n = ch * 64 + nt * 16 + (lane & 15);
    const int kb = kt * 32 + (lane >> 4) * 8;
    bf16x8 pk;
    #pragma unroll
    for (int j = 0; j < 8; ++j) pk[j] = (bf16)src[(size_t)(kb + j) * ncols + n];
    *(bf16x8*)&dst[(size_t)g * 8] = pk;
}

__global__ __launch_bounds__(256) void wpack_all_kernel(
    const float* __restrict__ W_kqv, const float* __restrict__ W_out,
    bf16* __restrict__ wkp, bf16* __restrict__ wop)
{
    const int bid = blockIdx.x;
    if (bid < 96) {
        wpack_body(W_kqv, wkp, N3, bid * 256 + threadIdx.x);
    } else {
        wpack_body(W_out, wop, O_DIM, (bid - 96) * 256 + threadIdx.x);
    }
}

// ---------------------------------------------------------------------------
// K1 v4: qkv proj -> qb (plain), kpk/vpk (fragment-packed). Proven R7.
// ---------------------------------------------------------------------------
__global__ __launch_bounds__(256) void qkv_proj_kernel(
    const float* __restrict__ query, const bf16* __restrict__ wkp,
    const float* __restrict__ b_kqv,
    bf16* __restrict__ qb, bf16* __restrict__ kpk, bf16* __restrict__ vpk)
{
    __shared__ __align__(16) bf16 Vt[64][68];
    const int m0 = blockIdx.x * 64;
    const int tid = threadIdx.x;
    const int lane = tid & 63, wave = tid >> 6, l15 = lane & 15, quad = lane >> 4;
    const int arow = wave * 16 + l15;

    bf16x8 af[8];
    {
        const float* qsrc = query + (size_t)(m0 + arow) * D_DIM + quad * 8;
        #pragma unroll
        for (int kt = 0; kt < 8; ++kt) {
            float4 f0 = *(const float4*)(qsrc + kt * 32);
            float4 f1 = *(const float4*)(qsrc + kt * 32 + 4);
            af[kt] = bf16x8{(bf16)f0.x, (bf16)f0.y, (bf16)f0.z, (bf16)f0.w,
                            (bf16)f1.x, (bf16)f1.y, (bf16)f1.z, (bf16)f1.w};
        }
    }

    for (int ch = 0; ch < 12; ++ch) {
        f32x4 acc[4];
        #pragma unroll
        for (int i = 0; i < 4; ++i)
            for (int r = 0; r < 4; ++r) acc[i][r] = 0.f;
        #pragma unroll
        for (int kt = 0; kt < 8; ++kt) {
            #pragma unroll
            for (int nt = 0; nt < 4; ++nt) {
                bf16x8 bb = *(const bf16x8*)&wkp[((((size_t)ch * 8 + kt) * 4 + nt) * 64 + lane) * 8];
                acc[nt] = MFMA16(af[kt], bb, acc[nt]);
            }
        }
        if (ch < 4) {
            #pragma unroll
            for (int nt = 0; nt < 4; ++nt) {
                const int c = ch * 64 + nt * 16 + l15;
                const float bias = b_kqv[c];
                #pragma unroll
                for (int r = 0; r < 4; ++r) {
                    const int m = m0 + wave * 16 + quad * 4 + r;
                    const int t = m >> 3, bi = m & 7;
                    qb[((size_t)bi * T_LEN + t) * P_DIM + c] = (bf16)((acc[nt][r] + bias) * 0.0625f);
                }
            }
        } else if (ch < 8) {
            #pragma unroll
            for (int nt = 0; nt < 4; ++nt) {
                const int c = ch * 64 + nt * 16 + l15;
                const float bias = b_kqv[c];
                const int kk = c - 256;
                const int c16 = kk >> 4, halfk = (kk >> 3) & 1, j = kk & 7;
                #pragma unroll
                for (int r = 0; r < 4; ++r) {
                    const int m = m0 + wave * 16 + quad * 4 + r;
                    const int t = m >> 3, bi = m & 7;
                    const int st32 = t >> 5, n31 = t & 31;
                    kpk[((((size_t)bi * 128 + st32) * 16 + c16) * 64 + halfk * 32 + n31) * 8 + j]
                        = (bf16)(acc[nt][r] + bias);
                }
            }
        } else {
            __syncthreads();
            #pragma unroll
            for (int nt = 0; nt < 4; ++nt) {
                const int c = ch * 64 + nt * 16 + l15;
                const float bias = b_kqv[c];
                #pragma unroll
                for (int r = 0; r < 4; ++r)
                    Vt[nt * 16 + l15][wave * 16 + quad * 4 + r] = (bf16)(acc[nt][r] + bias);
            }
            __syncthreads();
            const int t0g = m0 >> 3;
            const int s64 = t0g >> 6, ks = (t0g >> 4) & 3, halfv = (t0g >> 3) & 1;
            #pragma unroll
            for (int uu = 0; uu < 2; ++uu) {
                const int u = tid * 2 + uu;
                const int cl = u >> 3, bi = u & 7;
                bf16x8 pk;
                #pragma unroll
                for (int j = 0; j < 8; ++j) pk[j] = Vt[cl][j * 8 + bi];
                const int cc = (ch - 8) * 64 + cl;
                const int ptG = cc >> 5, n31 = cc & 31;
                *(bf16x8*)&vpk[((((size_t)bi * 64 + s64) * 4 + ks) * 8 + ptG) * 512
                               + (size_t)(halfv * 32 + n31) * 8] = pk;
            }
        }
    }
}

// ---------------------------------------------------------------------------
// K2 v7: flash attention (R0's proven inner loop, untouched) + fused out_proj
// epilogue.
//  - Inner loop identical to the 166.9 µs R0 kernel: kc2 ld -> QK -> bv ld ->
//    kpre ld -> exp -> lgkm barrier -> PV. 2 blocks/CU provide the cross-block
//    overlap R3 proved essential; no cross-iter V state (R1/R2 spill lesson).
//  - Epilogue: normalized O-tile (64 t-rows x full P=256, bf16 — identical
//    rounding to the old attn round-trip) staged in LDS At, then out_proj's
//    exact MFMA16 loop with packed wop frags, storing out f32 directly.
//    Kills the 16MB attn write + 16MB read + one dispatch.
//  - WRITE_SIZE expected: 32768 KB (out f32). Spill tripwire: any more = bad.
// ---------------------------------------------------------------------------
__global__ __launch_bounds__(256, 2) void flash_attn_kernel(
    const bf16* __restrict__ qb, const bf16* __restrict__ kpk,
    const bf16* __restrict__ vpk, const bf16* __restrict__ wop,
    const float* __restrict__ b_out, float* __restrict__ out)
{
    __shared__ __align__(16) bf16 Ps[2][64][LDS_P];   // 18.4 KB
    __shared__ float l_red[2][64];                    // [sh][row]
    __shared__ __align__(16) bf16 At[64][264];        // 33.8 KB (528B row, 33x16B)

    const int bid = blockIdx.x;
    const int b = bid & 7;                 // bid%8 == XCD: 4 MB KV per XCD L2
    const int t0 = (bid >> 3) * 64;
    const int tid = threadIdx.x;
    const int lane = tid & 63, wave = tid >> 6;
    const int l31 = lane & 31, half = lane >> 5;
    const int rg = wave & 1, sh = wave >> 1;

    // Q A-frags (row=lane&31, k=half*8+j), rows rg*32..+32 — proven layout
    bf16x8 qf[16];
    {
        const bf16* qrow = qb + ((size_t)b * T_LEN + t0 + rg * 32 + l31) * P_DIM + half * 8;
        #pragma unroll
        for (int kt = 0; kt < 16; ++kt) qf[kt] = *(const bf16x8*)(qrow + kt * 16);
    }

    f32x16 acc_o[2][2];   // [t-tile][p-tile]
    float l_part[16];
    #pragma unroll
    for (int i = 0; i < 16; ++i) {
        acc_o[0][0][i] = 0.f; acc_o[0][1][i] = 0.f;
        acc_o[1][0][i] = 0.f; acc_o[1][1][i] = 0.f;
        l_part[i] = 0.f;
    }

    const bf16* kfb = kpk + (size_t)b * 128 * 16 * 512;
    const bf16* vfb = vpk + (size_t)b * 64 * 4 * 8 * 512;

    // prime the K prefetch for s0 = 0
    bf16x8 kpre[8];
    {
        const bf16* kf0 = kfb + ((size_t)sh * 16 * 64 + lane) * 8;
        #pragma unroll
        for (int c = 0; c < 8; ++c) kpre[c] = *(const bf16x8*)(kf0 + (size_t)c * 512);
    }

    for (int s0 = 0; s0 < T_LEN; s0 += 64) {
        const int buf = (s0 >> 6) & 1;
        const bf16* kf  = kfb + (((size_t)((s0 >> 5) + sh)) * 16 * 64 + lane) * 8;
        const bf16* kfn = kfb + (((size_t)(((s0 + 64) >> 5) + sh)) * 16 * 64 + lane) * 8;

        // second half of current iter's K-frags: issue now, consumed after
        // the 8 prefetched MFMAs
        bf16x8 kc2[8];
        #pragma unroll
        for (int c = 0; c < 8; ++c) kc2[c] = *(const bf16x8*)(kf + (size_t)(8 + c) * 512);

        // QK: S quadrant [t=rg*32..][s=s0+sh*32..], K=256
        f32x16 accs;
        #pragma unroll
        for (int i = 0; i < 16; ++i) accs[i] = 0.f;
        #pragma unroll
        for (int c = 0; c < 8; ++c) accs = MFMA32(qf[c], kpre[c], accs);
        #pragma unroll
        for (int c = 0; c < 8; ++c) accs = MFMA32(qf[8 + c], kc2[c], accs);

        // V-frags for this iter (needed right after barrier) then next-iter K
        // prefetch — both fly through exp/Ps/barrier/PV.
        const bf16* vf = vfb + (((size_t)(s0 >> 6) * 4) * 8 + wave * 2) * 512 + (size_t)lane * 8;
        bf16x8 bv[8];
        #pragma unroll
        for (int ks = 0; ks < 4; ++ks) {
            bv[ks * 2]     = *(const bf16x8*)(vf + (size_t)ks * 8 * 512);
            bv[ks * 2 + 1] = *(const bf16x8*)(vf + (size_t)(ks * 8 + 1) * 512);
        }
        #pragma unroll
        for (int c = 0; c < 8; ++c) kpre[c] = *(const bf16x8*)(kfn + (size_t)c * 512);

        // P = exp(S); l accumulated on the bf16-rounded value (matches numerator)
        #pragma unroll
        for (int r = 0; r < 16; ++r) {
            float p = __expf(accs[r]);
            bf16 pb = (bf16)p;
            l_part[r] += (float)pb;
            int row = rg * 32 + (r & 3) + 8 * (r >> 2) + 4 * half;
            Ps[buf][row][sh * 32 + l31] = pb;
        }

        BARRIER_LGKM();   // Ps[buf] visible; global loads stay outstanding

        // PV: O[0..63][wave*64..+64) += P @ V
        #pragma unroll
        for (int ks = 0; ks < 4; ++ks) {
            bf16x8 ap0 = *(const bf16x8*)&Ps[buf][l31][ks * 16 + half * 8];
            bf16x8 ap1 = *(const bf16x8*)&Ps[buf][32 + l31][ks * 16 + half * 8];
            acc_o[0][0] = MFMA32(ap0, bv[ks * 2],     acc_o[0][0]);
            acc_o[0][1] = MFMA32(ap0, bv[ks * 2 + 1], acc_o[0][1]);
            acc_o[1][0] = MFMA32(ap1, bv[ks * 2],     acc_o[1][0]);
            acc_o[1][1] = MFMA32(ap1, bv[ks * 2 + 1], acc_o[1][1]);
        }
    }

    // ---- l reduction: across 32 cols (shuffle), then across sh waves (LDS) ----
    #pragma unroll
    for (int r = 0; r < 16; ++r) {
        float v = l_part[r];
        v += __shfl_xor(v, 1, 64);
        v += __shfl_xor(v, 2, 64);
        v += __shfl_xor(v, 4, 64);
        v += __shfl_xor(v, 8, 64);
        v += __shfl_xor(v, 16, 64);
        l_part[r] = v;
    }
    if (l31 == 0) {
        #pragma unroll
        for (int r = 0; r < 16; ++r) {
            const int row = rg * 32 + (r & 3) + 8 * (r >> 2) + 4 * half;
            l_red[sh][row] = l_part[r];
        }
    }
    __syncthreads();

    // ---- stage normalized O-tile in LDS (bf16 — same rounding as before) ----
    #pragma unroll
    for (int rt = 0; rt < 2; ++rt) {
        #pragma unroll
        for (int r = 0; r < 16; ++r) {
            const int row = rt * 32 + (r & 3) + 8 * (r >> 2) + 4 * half;
            const float linv = 1.0f / (l_red[0][row] + l_red[1][row]);
            At[row][wave * 64 + l31]      = (bf16)(acc_o[rt][0][r] * linv);
            At[row][wave * 64 + 32 + l31] = (bf16)(acc_o[rt][1][r] * linv);
        }
    }
    __syncthreads();

    // ---- fused out_proj: out-rows t0..t0+63 (batch b) = At @ W_out + b_out ----
    {
        const int l15 = lane & 15, quad = lane >> 4;
        const int arow = wave * 16 + l15;
        bf16x8 af[8];
        #pragma unroll
        for (int kt = 0; kt < 8; ++kt)
            af[kt] = *(const bf16x8*)&At[arow][quad * 8 + kt * 32];

        for (int ch = 0; ch < 4; ++ch) {
            f32x4 acc[4];
            #pragma unroll
            for (int i = 0; i < 4; ++i)
                for (int r = 0; r < 4; ++r) acc[i][r] = 0.f;
            #pragma unroll
            for (int kt = 0; kt < 8; ++kt) {
                #pragma unroll
                for (int nt = 0; nt < 4; ++nt) {
                    bf16x8 bb = *(const bf16x8*)&wop[((((size_t)ch * 8 + kt) * 4 + nt) * 64 + lane) * 8];
                    acc[nt] = MFMA16(af[kt], bb, acc[nt]);
                }
            }
            #pragma unroll
            for (int nt = 0; nt < 4; ++nt) {
                const int n = ch * 64 + nt * 16 + l15;
                const float bias = b_out[n];
                #pragma unroll
                for (int r = 0; r < 4; ++r) {
                    const int t = t0 + wave * 16 + quad * 4 + r;
                    out[((size_t)t * BATCH + b) * O_DIM + n] = acc[nt][r] + bias;
                }
            }
        }
    }
}

extern "C" void kernel_launch(void* const* d_in, const int* in_sizes, int n_in,
                              void* d_out, int out_size, void* d_ws, size_t ws_size,
                              hipStream_t stream) {
    const float* query = (const float*)d_in[0];
    const float* W_kqv = (const float*)d_in[1];
    const float* b_kqv = (const float*)d_in[2];
    const float* W_out = (const float*)d_in[3];
    const float* b_out = (const float*)d_in[4];
    float* out = (float*)d_out;

    const size_t BUF = (size_t)BATCH * T_LEN * P_DIM;
    bf16* qb   = (bf16*)d_ws;
    bf16* kpk  = qb + BUF;       // fragment-packed K
    bf16* vpk  = kpk + BUF;      // fragment-packed V
    bf16* scr  = vpk + BUF;      // scratch region (was attn — now weights only)
    bf16* wkp  = scr;            // packed W_kqv: 196,608 bf16
    bf16* wop  = scr + 262144;   // packed W_out: 65,536 bf16 (disjoint)

    wpack_all_kernel<<<128, 256, 0, stream>>>(W_kqv, W_out, wkp, wop);
    qkv_proj_kernel<<<512, 256, 0, stream>>>(query, wkp, b_kqv, qb, kpk, vpk);
    flash_attn_kernel<<<512, 256, 0, stream>>>(qb, kpk, vpk, wop, b_out, out);
}

// Round 5
// 270.148 us; speedup vs baseline: 1.2313x; 1.0213x over previous
//
#include <hip/hip_runtime.h>
#include <hip/hip_bf16.h>

#define T_LEN 4096
#define BATCH 8
#define D_DIM 256
#define P_DIM 256
#define O_DIM 256
#define N3    768

typedef __bf16 bf16;
typedef __attribute__((ext_vector_type(8))) __bf16 bf16x8;
typedef __attribute__((ext_vector_type(4))) __bf16 bf16x4;
typedef __attribute__((ext_vector_type(4))) float f32x4;
typedef __attribute__((ext_vector_type(16))) float f32x16;

#define MFMA16(a, b, c) __builtin_amdgcn_mfma_f32_16x16x32_bf16(a, b, c, 0, 0, 0)
#define MFMA32(a, b, c) __builtin_amdgcn_mfma_f32_32x32x16_bf16(a, b, c, 0, 0, 0)

#define LDS_P 72  // P rows: 144B stride

// lgkm-only barrier: drains LDS ops but leaves global/gload_lds in flight.
#define BARRIER_LGKM() __asm__ __volatile__("s_waitcnt lgkmcnt(0)\n\ts_barrier" ::: "memory")
// vmcnt(N)-counted barrier: used to wait for a staged LDS tile whose 8 loads
// are known to be the N newest outstanding vmem ops.
#define BARRIER_VM(N) __asm__ __volatile__("s_waitcnt vmcnt(" #N ")\n\ts_barrier" ::: "memory")

typedef __attribute__((address_space(1))) const unsigned int g_u32;
typedef __attribute__((address_space(3))) unsigned int l_u32;
// async global->LDS, 16B per lane; LDS dest is wave-uniform base + lane*16.
#define GLD16(gp, lp) __builtin_amdgcn_global_load_lds((g_u32*)(gp), (l_u32*)(lp), 16, 0, 0)

// ---------------------------------------------------------------------------
// K0: fragment-major weight pack (proven R6/R7), both weights in ONE dispatch.
// ---------------------------------------------------------------------------
__device__ __forceinline__ void wpack_body(
    const float* __restrict__ src, bf16* __restrict__ dst, int ncols, int g)
{
    const int lane = g & 63;
    const int idx = g >> 6;
    const int nt = idx & 3, kt = (idx >> 2) & 7, ch = idx >> 5;
    const int n = ch * 64 + nt * 16 + (lane & 15);
    const int kb = kt * 32 + (lane >> 4) * 8;
    bf16x8 pk;
    #pragma unroll
    for (int j = 0; j < 8; ++j) pk[j] = (bf16)src[(size_t)(kb + j) * ncols + n];
    *(bf16x8*)&dst[(size_t)g * 8] = pk;
}

__global__ __launch_bounds__(256) void wpack_all_kernel(
    const float* __restrict__ W_kqv, const float* __restrict__ W_out,
    bf16* __restrict__ wkp, bf16* __restrict__ wop)
{
    const int bid = blockIdx.x;
    if (bid < 96) {
        wpack_body(W_kqv, wkp, N3, bid * 256 + threadIdx.x);
    } else {
        wpack_body(W_out, wop, O_DIM, (bid - 96) * 256 + threadIdx.x);
    }
}

// ---------------------------------------------------------------------------
// K1 v5: qkv proj with LDS-staged weights.
//  - R4 post-mortem: qkv was ~85 µs vs ~25 µs roofline. Cause: 1:1 global
//    load:MFMA on the B operand (each wave re-loads the 32KB ch-tile from L2,
//    4x duplication per block, L1-thrashed) -> per-load vmcnt stalls.
//  - Fix: double-buffered LDS weight tile staged via global_load_lds width=16.
//    tile(ch+1) issued at iter-ch start = the 8 NEWEST vmem ops, so
//    BARRIER_VM(8) guarantees tile(ch) landed without draining tile(ch+1).
//    End-of-iter BARRIER_LGKM frees the buffer for overwrite next iter.
//  - bb reads: lane-contiguous ds_read_b128 (conflict-free).
//  - V-transpose syncs become lgkm-only so staged loads stay in flight.
//  - Numerically bit-identical to v4 (same values, same MFMA order).
// ---------------------------------------------------------------------------
__global__ __launch_bounds__(256) void qkv_proj_kernel(
    const float* __restrict__ query, const bf16* __restrict__ wkp,
    const float* __restrict__ b_kqv,
    bf16* __restrict__ qb, bf16* __restrict__ kpk, bf16* __restrict__ vpk)
{
    __shared__ __align__(16) bf16 Vt[64][68];
    __shared__ __align__(16) bf16 Wb[2][16384];   // 2 x 32KB ch-tile
    const int m0 = blockIdx.x * 64;
    const int tid = threadIdx.x;
    const int lane = tid & 63, wave = tid >> 6, l15 = lane & 15, quad = lane >> 4;
    const int arow = wave * 16 + l15;

#define STAGE_W(CH, NB)                                                       \
    {                                                                         \
        const bf16* gsrc = wkp + (size_t)(CH) * 16384;                        \
        _Pragma("unroll")                                                     \
        for (int j = 0; j < 8; ++j)                                           \
            GLD16(gsrc + ((size_t)j * 256 + tid) * 8,                         \
                  &Wb[NB][(j * 256 + wave * 64) * 8]);                        \
    }

    STAGE_W(0, 0);   // prime tile 0

    bf16x8 af[8];
    {
        const float* qsrc = query + (size_t)(m0 + arow) * D_DIM + quad * 8;
        #pragma unroll
        for (int kt = 0; kt < 8; ++kt) {
            float4 f0 = *(const float4*)(qsrc + kt * 32);
            float4 f1 = *(const float4*)(qsrc + kt * 32 + 4);
            af[kt] = bf16x8{(bf16)f0.x, (bf16)f0.y, (bf16)f0.z, (bf16)f0.w,
                            (bf16)f1.x, (bf16)f1.y, (bf16)f1.z, (bf16)f1.w};
        }
    }

    for (int ch = 0; ch < 12; ++ch) {
        const int buf = ch & 1;
        if (ch < 11) {
            STAGE_W(ch + 1, buf ^ 1);   // 8 newest vmem ops
            BARRIER_VM(8);              // tile(ch) landed in Wb[buf], all waves
        } else {
            BARRIER_VM(0);
        }

        f32x4 acc[4];
        #pragma unroll
        for (int i = 0; i < 4; ++i)
            for (int r = 0; r < 4; ++r) acc[i][r] = 0.f;
        #pragma unroll
        for (int kt = 0; kt < 8; ++kt) {
            #pragma unroll
            for (int nt = 0; nt < 4; ++nt) {
                bf16x8 bb = *(const bf16x8*)&Wb[buf][((kt * 4 + nt) * 64 + lane) * 8];
                acc[nt] = MFMA16(af[kt], bb, acc[nt]);
            }
        }
        if (ch < 4) {
            #pragma unroll
            for (int nt = 0; nt < 4; ++nt) {
                const int c = ch * 64 + nt * 16 + l15;
                const float bias = b_kqv[c];
                #pragma unroll
                for (int r = 0; r < 4; ++r) {
                    const int m = m0 + wave * 16 + quad * 4 + r;
                    const int t = m >> 3, bi = m & 7;
                    qb[((size_t)bi * T_LEN + t) * P_DIM + c] = (bf16)((acc[nt][r] + bias) * 0.0625f);
                }
            }
        } else if (ch < 8) {
            #pragma unroll
            for (int nt = 0; nt < 4; ++nt) {
                const int c = ch * 64 + nt * 16 + l15;
                const float bias = b_kqv[c];
                const int kk = c - 256;
                const int c16 = kk >> 4, halfk = (kk >> 3) & 1, j = kk & 7;
                #pragma unroll
                for (int r = 0; r < 4; ++r) {
                    const int m = m0 + wave * 16 + quad * 4 + r;
                    const int t = m >> 3, bi = m & 7;
                    const int st32 = t >> 5, n31 = t & 31;
                    kpk[((((size_t)bi * 128 + st32) * 16 + c16) * 64 + halfk * 32 + n31) * 8 + j]
                        = (bf16)(acc[nt][r] + bias);
                }
            }
        } else {
            BARRIER_LGKM();   // Vt free (prev V-ch pack reads retired)
            #pragma unroll
            for (int nt = 0; nt < 4; ++nt) {
                const int c = ch * 64 + nt * 16 + l15;
                const float bias = b_kqv[c];
                #pragma unroll
                for (int r = 0; r < 4; ++r)
                    Vt[nt * 16 + l15][wave * 16 + quad * 4 + r] = (bf16)(acc[nt][r] + bias);
            }
            BARRIER_LGKM();   // Vt visible
            const int t0g = m0 >> 3;
            const int s64 = t0g >> 6, ks = (t0g >> 4) & 3, halfv = (t0g >> 3) & 1;
            #pragma unroll
            for (int uu = 0; uu < 2; ++uu) {
                const int u = tid * 2 + uu;
                const int cl = u >> 3, bi = u & 7;
                bf16x8 pk;
                #pragma unroll
                for (int j = 0; j < 8; ++j) pk[j] = Vt[cl][j * 8 + bi];
                const int cc = (ch - 8) * 64 + cl;
                const int ptG = cc >> 5, n31 = cc & 31;
                *(bf16x8*)&vpk[((((size_t)bi * 64 + s64) * 4 + ks) * 8 + ptG) * 512
                               + (size_t)(halfv * 32 + n31) * 8] = pk;
            }
        }
        BARRIER_LGKM();   // all waves done reading Wb[buf] -> free for overwrite
    }
#undef STAGE_W
}

// ---------------------------------------------------------------------------
// K2 v7: flash attention (R0's proven inner loop) + fused out_proj epilogue.
// Unchanged from R4 (173.6 µs, verified: WRITE=32768KB, no spills).
// ---------------------------------------------------------------------------
__global__ __launch_bounds__(256, 2) void flash_attn_kernel(
    const bf16* __restrict__ qb, const bf16* __restrict__ kpk,
    const bf16* __restrict__ vpk, const bf16* __restrict__ wop,
    const float* __restrict__ b_out, float* __restrict__ out)
{
    __shared__ __align__(16) bf16 Ps[2][64][LDS_P];   // 18.4 KB
    __shared__ float l_red[2][64];                    // [sh][row]
    __shared__ __align__(16) bf16 At[64][264];        // 33.8 KB

    const int bid = blockIdx.x;
    const int b = bid & 7;                 // bid%8 == XCD: 4 MB KV per XCD L2
    const int t0 = (bid >> 3) * 64;
    const int tid = threadIdx.x;
    const int lane = tid & 63, wave = tid >> 6;
    const int l31 = lane & 31, half = lane >> 5;
    const int rg = wave & 1, sh = wave >> 1;

    // Q A-frags (row=lane&31, k=half*8+j), rows rg*32..+32 — proven layout
    bf16x8 qf[16];
    {
        const bf16* qrow = qb + ((size_t)b * T_LEN + t0 + rg * 32 + l31) * P_DIM + half * 8;
        #pragma unroll
        for (int kt = 0; kt < 16; ++kt) qf[kt] = *(const bf16x8*)(qrow + kt * 16);
    }

    f32x16 acc_o[2][2];   // [t-tile][p-tile]
    float l_part[16];
    #pragma unroll
    for (int i = 0; i < 16; ++i) {
        acc_o[0][0][i] = 0.f; acc_o[0][1][i] = 0.f;
        acc_o[1][0][i] = 0.f; acc_o[1][1][i] = 0.f;
        l_part[i] = 0.f;
    }

    const bf16* kfb = kpk + (size_t)b * 128 * 16 * 512;
    const bf16* vfb = vpk + (size_t)b * 64 * 4 * 8 * 512;

    // prime the K prefetch for s0 = 0
    bf16x8 kpre[8];
    {
        const bf16* kf0 = kfb + ((size_t)sh * 16 * 64 + lane) * 8;
        #pragma unroll
        for (int c = 0; c < 8; ++c) kpre[c] = *(const bf16x8*)(kf0 + (size_t)c * 512);
    }

    for (int s0 = 0; s0 < T_LEN; s0 += 64) {
        const int buf = (s0 >> 6) & 1;
        const bf16* kf  = kfb + (((size_t)((s0 >> 5) + sh)) * 16 * 64 + lane) * 8;
        const bf16* kfn = kfb + (((size_t)(((s0 + 64) >> 5) + sh)) * 16 * 64 + lane) * 8;

        // second half of current iter's K-frags
        bf16x8 kc2[8];
        #pragma unroll
        for (int c = 0; c < 8; ++c) kc2[c] = *(const bf16x8*)(kf + (size_t)(8 + c) * 512);

        // QK: S quadrant [t=rg*32..][s=s0+sh*32..], K=256
        f32x16 accs;
        #pragma unroll
        for (int i = 0; i < 16; ++i) accs[i] = 0.f;
        #pragma unroll
        for (int c = 0; c < 8; ++c) accs = MFMA32(qf[c], kpre[c], accs);
        #pragma unroll
        for (int c = 0; c < 8; ++c) accs = MFMA32(qf[8 + c], kc2[c], accs);

        // V-frags for this iter, then next-iter K prefetch — both fly through
        // exp/Ps/barrier/PV.
        const bf16* vf = vfb + (((size_t)(s0 >> 6) * 4) * 8 + wave * 2) * 512 + (size_t)lane * 8;
        bf16x8 bv[8];
        #pragma unroll
        for (int ks = 0; ks < 4; ++ks) {
            bv[ks * 2]     = *(const bf16x8*)(vf + (size_t)ks * 8 * 512);
            bv[ks * 2 + 1] = *(const bf16x8*)(vf + (size_t)(ks * 8 + 1) * 512);
        }
        #pragma unroll
        for (int c = 0; c < 8; ++c) kpre[c] = *(const bf16x8*)(kfn + (size_t)c * 512);

        // P = exp(S); l accumulated on the bf16-rounded value
        #pragma unroll
        for (int r = 0; r < 16; ++r) {
            float p = __expf(accs[r]);
            bf16 pb = (bf16)p;
            l_part[r] += (float)pb;
            int row = rg * 32 + (r & 3) + 8 * (r >> 2) + 4 * half;
            Ps[buf][row][sh * 32 + l31] = pb;
        }

        BARRIER_LGKM();   // Ps[buf] visible; global loads stay outstanding

        // PV: O[0..63][wave*64..+64) += P @ V
        #pragma unroll
        for (int ks = 0; ks < 4; ++ks) {
            bf16x8 ap0 = *(const bf16x8*)&Ps[buf][l31][ks * 16 + half * 8];
            bf16x8 ap1 = *(const bf16x8*)&Ps[buf][32 + l31][ks * 16 + half * 8];
            acc_o[0][0] = MFMA32(ap0, bv[ks * 2],     acc_o[0][0]);
            acc_o[0][1] = MFMA32(ap0, bv[ks * 2 + 1], acc_o[0][1]);
            acc_o[1][0] = MFMA32(ap1, bv[ks * 2],     acc_o[1][0]);
            acc_o[1][1] = MFMA32(ap1, bv[ks * 2 + 1], acc_o[1][1]);
        }
    }

    // ---- l reduction: across 32 cols (shuffle), then across sh waves (LDS) ----
    #pragma unroll
    for (int r = 0; r < 16; ++r) {
        float v = l_part[r];
        v += __shfl_xor(v, 1, 64);
        v += __shfl_xor(v, 2, 64);
        v += __shfl_xor(v, 4, 64);
        v += __shfl_xor(v, 8, 64);
        v += __shfl_xor(v, 16, 64);
        l_part[r] = v;
    }
    if (l31 == 0) {
        #pragma unroll
        for (int r = 0; r < 16; ++r) {
            const int row = rg * 32 + (r & 3) + 8 * (r >> 2) + 4 * half;
            l_red[sh][row] = l_part[r];
        }
    }
    __syncthreads();

    // ---- stage normalized O-tile in LDS (bf16 — same rounding as before) ----
    #pragma unroll
    for (int rt = 0; rt < 2; ++rt) {
        #pragma unroll
        for (int r = 0; r < 16; ++r) {
            const int row = rt * 32 + (r & 3) + 8 * (r >> 2) + 4 * half;
            const float linv = 1.0f / (l_red[0][row] + l_red[1][row]);
            At[row][wave * 64 + l31]      = (bf16)(acc_o[rt][0][r] * linv);
            At[row][wave * 64 + 32 + l31] = (bf16)(acc_o[rt][1][r] * linv);
        }
    }
    __syncthreads();

    // ---- fused out_proj: out-rows t0..t0+63 (batch b) = At @ W_out + b_out ----
    {
        const int l15 = lane & 15, quad = lane >> 4;
        const int arow = wave * 16 + l15;
        bf16x8 af[8];
        #pragma unroll
        for (int kt = 0; kt < 8; ++kt)
            af[kt] = *(const bf16x8*)&At[arow][quad * 8 + kt * 32];

        for (int ch = 0; ch < 4; ++ch) {
            f32x4 acc[4];
            #pragma unroll
            for (int i = 0; i < 4; ++i)
                for (int r = 0; r < 4; ++r) acc[i][r] = 0.f;
            #pragma unroll
            for (int kt = 0; kt < 8; ++kt) {
                #pragma unroll
                for (int nt = 0; nt < 4; ++nt) {
                    bf16x8 bb = *(const bf16x8*)&wop[((((size_t)ch * 8 + kt) * 4 + nt) * 64 + lane) * 8];
                    acc[nt] = MFMA16(af[kt], bb, acc[nt]);
                }
            }
            #pragma unroll
            for (int nt = 0; nt < 4; ++nt) {
                const int n = ch * 64 + nt * 16 + l15;
                const float bias = b_out[n];
                #pragma unroll
                for (int r = 0; r < 4; ++r) {
                    const int t = t0 + wave * 16 + quad * 4 + r;
                    out[((size_t)t * BATCH + b) * O_DIM + n] = acc[nt][r] + bias;
                }
            }
        }
    }
}

extern "C" void kernel_launch(void* const* d_in, const int* in_sizes, int n_in,
                              void* d_out, int out_size, void* d_ws, size_t ws_size,
                              hipStream_t stream) {
    const float* query = (const float*)d_in[0];
    const float* W_kqv = (const float*)d_in[1];
    const float* b_kqv = (const float*)d_in[2];
    const float* W_out = (const float*)d_in[3];
    const float* b_out = (const float*)d_in[4];
    float* out = (float*)d_out;

    const size_t BUF = (size_t)BATCH * T_LEN * P_DIM;
    bf16* qb   = (bf16*)d_ws;
    bf16* kpk  = qb + BUF;       // fragment-packed K
    bf16* vpk  = kpk + BUF;      // fragment-packed V
    bf16* scr  = vpk + BUF;      // scratch region (weights)
    bf16* wkp  = scr;            // packed W_kqv: 196,608 bf16
    bf16* wop  = scr + 262144;   // packed W_out: 65,536 bf16 (disjoint)

    wpack_all_kernel<<<128, 256, 0, stream>>>(W_kqv, W_out, wkp, wop);
    qkv_proj_kernel<<<512, 256, 0, stream>>>(query, wkp, b_kqv, qb, kpk, vpk);
    flash_attn_kernel<<<512, 256, 0, stream>>>(qb, kpk, vpk, wop, b_out, out);
}

// Round 6
// 267.877 us; speedup vs baseline: 1.2418x; 1.0085x over previous
//
#include <hip/hip_runtime.h>
#include <hip/hip_bf16.h>

#define T_LEN 4096
#define BATCH 8
#define D_DIM 256
#define P_DIM 256
#define O_DIM 256
#define N3    768

typedef __bf16 bf16;
typedef __attribute__((ext_vector_type(8))) __bf16 bf16x8;
typedef __attribute__((ext_vector_type(4))) __bf16 bf16x4;
typedef __attribute__((ext_vector_type(4))) float f32x4;
typedef __attribute__((ext_vector_type(16))) float f32x16;

#define MFMA16(a, b, c) __builtin_amdgcn_mfma_f32_16x16x32_bf16(a, b, c, 0, 0, 0)
#define MFMA32(a, b, c) __builtin_amdgcn_mfma_f32_32x32x16_bf16(a, b, c, 0, 0, 0)

#define LDS_P 72  // P rows: 144B stride

// lgkm-only barrier: drains LDS ops but leaves global/gload_lds in flight.
#define BARRIER_LGKM() __asm__ __volatile__("s_waitcnt lgkmcnt(0)\n\ts_barrier" ::: "memory")
// vmcnt(N)-counted barrier: wait for a staged LDS tile whose loads are the N
// newest outstanding vmem ops.
#define BARRIER_VM(N) __asm__ __volatile__("s_waitcnt vmcnt(" #N ")\n\ts_barrier" ::: "memory")

typedef __attribute__((address_space(1))) const unsigned int g_u32;
typedef __attribute__((address_space(3))) unsigned int l_u32;
// async global->LDS, 16B per lane; LDS dest is wave-uniform base + lane*16.
#define GLD16(gp, lp) __builtin_amdgcn_global_load_lds((g_u32*)(gp), (l_u32*)(lp), 16, 0, 0)

// ---------------------------------------------------------------------------
// K0: fragment-major weight pack (proven R6/R7), both weights in ONE dispatch.
// ---------------------------------------------------------------------------
__device__ __forceinline__ void wpack_body(
    const float* __restrict__ src, bf16* __restrict__ dst, int ncols, int g)
{
    const int lane = g & 63;
    const int idx = g >> 6;
    const int nt = idx & 3, kt = (idx >> 2) & 7, ch = idx >> 5;
    const int n = ch * 64 + nt * 16 + (lane & 15);
    const int kb = kt * 32 + (lane >> 4) * 8;
    bf16x8 pk;
    #pragma unroll
    for (int j = 0; j < 8; ++j) pk[j] = (bf16)src[(size_t)(kb + j) * ncols + n];
    *(bf16x8*)&dst[(size_t)g * 8] = pk;
}

__global__ __launch_bounds__(256) void wpack_all_kernel(
    const float* __restrict__ W_kqv, const float* __restrict__ W_out,
    bf16* __restrict__ wkp, bf16* __restrict__ wop)
{
    const int bid = blockIdx.x;
    if (bid < 96) {
        wpack_body(W_kqv, wkp, N3, bid * 256 + threadIdx.x);
    } else {
        wpack_body(W_out, wop, O_DIM, (bid - 96) * 256 + threadIdx.x);
    }
}

// ---------------------------------------------------------------------------
// K1 v6: qkv proj — LDS-staged weights + LDS-transposed VECTOR stores.
//  - R5 post-mortem: weight staging bought ~0; qkv (~90 µs vs 13 µs HBM floor)
//    is STORE-instruction-bound: 128 scalar 2B global stores/thread (qb+kpk),
//    each scattering 4-8 segments in the VMEM pipe.
//  - Fix: per ch-tile, stage outputs into Tt[64][72] (m-major for q/k; the V
//    path already transposes via LDS), then 2x bf16x8 stores per thread.
//      qb : 8 lanes -> 128B contiguous.
//      kpk: lane remap (cl=u>>6, bi=(u>>3)&7, idx=u&7) -> one aligned 16B
//           fragment per lane, 8 consecutive lanes cover consecutive n31
//           -> 128B contiguous per (bi,c16,halfk) group.
//    Global store instrs/thread: 128 scalar -> 16 vector (8x fewer).
//  - Values pass identical (bf16)((acc+bias)[*0.0625f]) rounding ->
//    bit-identical outputs.
//  - Barriers/ch: [STAGE_W; VM(8)] -> MFMA -> LGKM (Tt free) -> Tt writes ->
//    LGKM (Tt visible) -> Tt reads + vector stores. Wb[buf^1] staged at iter
//    start is untouched until next iter's VM barrier; Tt protected by the
//    per-iter Tt-free barrier.
// ---------------------------------------------------------------------------
__global__ __launch_bounds__(256) void qkv_proj_kernel(
    const float* __restrict__ query, const bf16* __restrict__ wkp,
    const float* __restrict__ b_kqv,
    bf16* __restrict__ qb, bf16* __restrict__ kpk, bf16* __restrict__ vpk)
{
    __shared__ __align__(16) bf16 Tt[64][72];     // 9 KB transpose tile
    __shared__ __align__(16) bf16 Wb[2][16384];   // 2 x 32KB ch-tile
    const int m0 = blockIdx.x * 64;
    const int t0g = m0 >> 3;
    const int tid = threadIdx.x;
    const int lane = tid & 63, wave = tid >> 6, l15 = lane & 15, quad = lane >> 4;
    const int arow = wave * 16 + l15;

#define STAGE_W(CH, NB)                                                       \
    {                                                                         \
        const bf16* gsrc = wkp + (size_t)(CH) * 16384;                        \
        _Pragma("unroll")                                                     \
        for (int j = 0; j < 8; ++j)                                           \
            GLD16(gsrc + ((size_t)j * 256 + tid) * 8,                         \
                  &Wb[NB][(j * 256 + wave * 64) * 8]);                        \
    }

    STAGE_W(0, 0);   // prime tile 0

    bf16x8 af[8];
    {
        const float* qsrc = query + (size_t)(m0 + arow) * D_DIM + quad * 8;
        #pragma unroll
        for (int kt = 0; kt < 8; ++kt) {
            float4 f0 = *(const float4*)(qsrc + kt * 32);
            float4 f1 = *(const float4*)(qsrc + kt * 32 + 4);
            af[kt] = bf16x8{(bf16)f0.x, (bf16)f0.y, (bf16)f0.z, (bf16)f0.w,
                            (bf16)f1.x, (bf16)f1.y, (bf16)f1.z, (bf16)f1.w};
        }
    }

    for (int ch = 0; ch < 12; ++ch) {
        const int buf = ch & 1;
        if (ch < 11) {
            STAGE_W(ch + 1, buf ^ 1);   // 8 newest vmem ops
            BARRIER_VM(8);              // tile(ch) landed in Wb[buf], all waves
        } else {
            BARRIER_VM(0);
        }

        f32x4 acc[4];
        #pragma unroll
        for (int i = 0; i < 4; ++i)
            for (int r = 0; r < 4; ++r) acc[i][r] = 0.f;
        #pragma unroll
        for (int kt = 0; kt < 8; ++kt) {
            #pragma unroll
            for (int nt = 0; nt < 4; ++nt) {
                bf16x8 bb = *(const bf16x8*)&Wb[buf][((kt * 4 + nt) * 64 + lane) * 8];
                acc[nt] = MFMA16(af[kt], bb, acc[nt]);
            }
        }

        BARRIER_LGKM();   // Tt free (previous iter's readers retired)

        if (ch < 8) {
            // q/k: stage m-major (scaled q), bit-identical rounding
            const float scale = (ch < 4) ? 0.0625f : 1.0f;
            #pragma unroll
            for (int nt = 0; nt < 4; ++nt) {
                const int c = ch * 64 + nt * 16 + l15;
                const float bias = b_kqv[c];
                #pragma unroll
                for (int r = 0; r < 4; ++r)
                    Tt[wave * 16 + quad * 4 + r][nt * 16 + l15]
                        = (bf16)((acc[nt][r] + bias) * scale);
            }
            BARRIER_LGKM();   // Tt visible
            if (ch < 4) {
                #pragma unroll
                for (int uu = 0; uu < 2; ++uu) {
                    const int u = tid * 2 + uu;
                    const int row = u >> 3, cl = u & 7;
                    bf16x8 pk = *(const bf16x8*)&Tt[row][cl * 8];
                    const int m = m0 + row, t = m >> 3, bi = m & 7;
                    *(bf16x8*)&qb[((size_t)bi * T_LEN + t) * P_DIM + ch * 64 + cl * 8] = pk;
                }
            } else {
                #pragma unroll
                for (int uu = 0; uu < 2; ++uu) {
                    const int u = tid * 2 + uu;
                    const int cl = u >> 6, bi = (u >> 3) & 7, idx = u & 7;
                    const int row = idx * 8 + bi;
                    bf16x8 pk = *(const bf16x8*)&Tt[row][cl * 8];
                    const int t = t0g + idx;
                    const int st32 = t >> 5, n31 = t & 31;
                    const int c16 = (ch - 4) * 4 + (cl >> 1), halfk = cl & 1;
                    *(bf16x8*)&kpk[(size_t)((((bi * 128 + st32) * 16 + c16) * 64
                                             + halfk * 32 + n31) * 8)] = pk;
                }
            }
        } else {
            // V: stage c-major (fragment pack needs m-gather) — proven path
            #pragma unroll
            for (int nt = 0; nt < 4; ++nt) {
                const int c = ch * 64 + nt * 16 + l15;
                const float bias = b_kqv[c];
                #pragma unroll
                for (int r = 0; r < 4; ++r)
                    Tt[nt * 16 + l15][wave * 16 + quad * 4 + r] = (bf16)(acc[nt][r] + bias);
            }
            BARRIER_LGKM();   // Tt visible
            const int s64 = t0g >> 6, ks = (t0g >> 4) & 3, halfv = (t0g >> 3) & 1;
            #pragma unroll
            for (int uu = 0; uu < 2; ++uu) {
                const int u = tid * 2 + uu;
                const int cl = u >> 3, bi = u & 7;
                bf16x8 pk;
                #pragma unroll
                for (int j = 0; j < 8; ++j) pk[j] = Tt[cl][j * 8 + bi];
                const int cc = (ch - 8) * 64 + cl;
                const int ptG = cc >> 5, n31 = cc & 31;
                *(bf16x8*)&vpk[((((size_t)bi * 64 + s64) * 4 + ks) * 8 + ptG) * 512
                               + (size_t)(halfv * 32 + n31) * 8] = pk;
            }
        }
    }
#undef STAGE_W
}

// ---------------------------------------------------------------------------
// K2 v7: flash attention (R0's proven inner loop) + fused out_proj epilogue.
// Unchanged from R4 (173.6 µs, verified: WRITE=32768KB, no spills).
// ---------------------------------------------------------------------------
__global__ __launch_bounds__(256, 2) void flash_attn_kernel(
    const bf16* __restrict__ qb, const bf16* __restrict__ kpk,
    const bf16* __restrict__ vpk, const bf16* __restrict__ wop,
    const float* __restrict__ b_out, float* __restrict__ out)
{
    __shared__ __align__(16) bf16 Ps[2][64][LDS_P];   // 18.4 KB
    __shared__ float l_red[2][64];                    // [sh][row]
    __shared__ __align__(16) bf16 At[64][264];        // 33.8 KB

    const int bid = blockIdx.x;
    const int b = bid & 7;                 // bid%8 == XCD: 4 MB KV per XCD L2
    const int t0 = (bid >> 3) * 64;
    const int tid = threadIdx.x;
    const int lane = tid & 63, wave = tid >> 6;
    const int l31 = lane & 31, half = lane >> 5;
    const int rg = wave & 1, sh = wave >> 1;

    // Q A-frags (row=lane&31, k=half*8+j), rows rg*32..+32 — proven layout
    bf16x8 qf[16];
    {
        const bf16* qrow = qb + ((size_t)b * T_LEN + t0 + rg * 32 + l31) * P_DIM + half * 8;
        #pragma unroll
        for (int kt = 0; kt < 16; ++kt) qf[kt] = *(const bf16x8*)(qrow + kt * 16);
    }

    f32x16 acc_o[2][2];   // [t-tile][p-tile]
    float l_part[16];
    #pragma unroll
    for (int i = 0; i < 16; ++i) {
        acc_o[0][0][i] = 0.f; acc_o[0][1][i] = 0.f;
        acc_o[1][0][i] = 0.f; acc_o[1][1][i] = 0.f;
        l_part[i] = 0.f;
    }

    const bf16* kfb = kpk + (size_t)b * 128 * 16 * 512;
    const bf16* vfb = vpk + (size_t)b * 64 * 4 * 8 * 512;

    // prime the K prefetch for s0 = 0
    bf16x8 kpre[8];
    {
        const bf16* kf0 = kfb + ((size_t)sh * 16 * 64 + lane) * 8;
        #pragma unroll
        for (int c = 0; c < 8; ++c) kpre[c] = *(const bf16x8*)(kf0 + (size_t)c * 512);
    }

    for (int s0 = 0; s0 < T_LEN; s0 += 64) {
        const int buf = (s0 >> 6) & 1;
        const bf16* kf  = kfb + (((size_t)((s0 >> 5) + sh)) * 16 * 64 + lane) * 8;
        const bf16* kfn = kfb + (((size_t)(((s0 + 64) >> 5) + sh)) * 16 * 64 + lane) * 8;

        // second half of current iter's K-frags
        bf16x8 kc2[8];
        #pragma unroll
        for (int c = 0; c < 8; ++c) kc2[c] = *(const bf16x8*)(kf + (size_t)(8 + c) * 512);

        // QK: S quadrant [t=rg*32..][s=s0+sh*32..], K=256
        f32x16 accs;
        #pragma unroll
        for (int i = 0; i < 16; ++i) accs[i] = 0.f;
        #pragma unroll
        for (int c = 0; c < 8; ++c) accs = MFMA32(qf[c], kpre[c], accs);
        #pragma unroll
        for (int c = 0; c < 8; ++c) accs = MFMA32(qf[8 + c], kc2[c], accs);

        // V-frags for this iter, then next-iter K prefetch — both fly through
        // exp/Ps/barrier/PV.
        const bf16* vf = vfb + (((size_t)(s0 >> 6) * 4) * 8 + wave * 2) * 512 + (size_t)lane * 8;
        bf16x8 bv[8];
        #pragma unroll
        for (int ks = 0; ks < 4; ++ks) {
            bv[ks * 2]     = *(const bf16x8*)(vf + (size_t)ks * 8 * 512);
            bv[ks * 2 + 1] = *(const bf16x8*)(vf + (size_t)(ks * 8 + 1) * 512);
        }
        #pragma unroll
        for (int c = 0; c < 8; ++c) kpre[c] = *(const bf16x8*)(kfn + (size_t)c * 512);

        // P = exp(S); l accumulated on the bf16-rounded value
        #pragma unroll
        for (int r = 0; r < 16; ++r) {
            float p = __expf(accs[r]);
            bf16 pb = (bf16)p;
            l_part[r] += (float)pb;
            int row = rg * 32 + (r & 3) + 8 * (r >> 2) + 4 * half;
            Ps[buf][row][sh * 32 + l31] = pb;
        }

        BARRIER_LGKM();   // Ps[buf] visible; global loads stay outstanding

        // PV: O[0..63][wave*64..+64) += P @ V
        #pragma unroll
        for (int ks = 0; ks < 4; ++ks) {
            bf16x8 ap0 = *(const bf16x8*)&Ps[buf][l31][ks * 16 + half * 8];
            bf16x8 ap1 = *(const bf16x8*)&Ps[buf][32 + l31][ks * 16 + half * 8];
            acc_o[0][0] = MFMA32(ap0, bv[ks * 2],     acc_o[0][0]);
            acc_o[0][1] = MFMA32(ap0, bv[ks * 2 + 1], acc_o[0][1]);
            acc_o[1][0] = MFMA32(ap1, bv[ks * 2],     acc_o[1][0]);
            acc_o[1][1] = MFMA32(ap1, bv[ks * 2 + 1], acc_o[1][1]);
        }
    }

    // ---- l reduction: across 32 cols (shuffle), then across sh waves (LDS) ----
    #pragma unroll
    for (int r = 0; r < 16; ++r) {
        float v = l_part[r];
        v += __shfl_xor(v, 1, 64);
        v += __shfl_xor(v, 2, 64);
        v += __shfl_xor(v, 4, 64);
        v += __shfl_xor(v, 8, 64);
        v += __shfl_xor(v, 16, 64);
        l_part[r] = v;
    }
    if (l31 == 0) {
        #pragma unroll
        for (int r = 0; r < 16; ++r) {
            const int row = rg * 32 + (r & 3) + 8 * (r >> 2) + 4 * half;
            l_red[sh][row] = l_part[r];
        }
    }
    __syncthreads();

    // ---- stage normalized O-tile in LDS (bf16 — same rounding as before) ----
    #pragma unroll
    for (int rt = 0; rt < 2; ++rt) {
        #pragma unroll
        for (int r = 0; r < 16; ++r) {
            const int row = rt * 32 + (r & 3) + 8 * (r >> 2) + 4 * half;
            const float linv = 1.0f / (l_red[0][row] + l_red[1][row]);
            At[row][wave * 64 + l31]      = (bf16)(acc_o[rt][0][r] * linv);
            At[row][wave * 64 + 32 + l31] = (bf16)(acc_o[rt][1][r] * linv);
        }
    }
    __syncthreads();

    // ---- fused out_proj: out-rows t0..t0+63 (batch b) = At @ W_out + b_out ----
    {
        const int l15 = lane & 15, quad = lane >> 4;
        const int arow = wave * 16 + l15;
        bf16x8 af[8];
        #pragma unroll
        for (int kt = 0; kt < 8; ++kt)
            af[kt] = *(const bf16x8*)&At[arow][quad * 8 + kt * 32];

        for (int ch = 0; ch < 4; ++ch) {
            f32x4 acc[4];
            #pragma unroll
            for (int i = 0; i < 4; ++i)
                for (int r = 0; r < 4; ++r) acc[i][r] = 0.f;
            #pragma unroll
            for (int kt = 0; kt < 8; ++kt) {
                #pragma unroll
                for (int nt = 0; nt < 4; ++nt) {
                    bf16x8 bb = *(const bf16x8*)&wop[((((size_t)ch * 8 + kt) * 4 + nt) * 64 + lane) * 8];
                    acc[nt] = MFMA16(af[kt], bb, acc[nt]);
                }
            }
            #pragma unroll
            for (int nt = 0; nt < 4; ++nt) {
                const int n = ch * 64 + nt * 16 + l15;
                const float bias = b_out[n];
                #pragma unroll
                for (int r = 0; r < 4; ++r) {
                    const int t = t0 + wave * 16 + quad * 4 + r;
                    out[((size_t)t * BATCH + b) * O_DIM + n] = acc[nt][r] + bias;
                }
            }
        }
    }
}

extern "C" void kernel_launch(void* const* d_in, const int* in_sizes, int n_in,
                              void* d_out, int out_size, void* d_ws, size_t ws_size,
                              hipStream_t stream) {
    const float* query = (const float*)d_in[0];
    const float* W_kqv = (const float*)d_in[1];
    const float* b_kqv = (const float*)d_in[2];
    const float* W_out = (const float*)d_in[3];
    const float* b_out = (const float*)d_in[4];
    float* out = (float*)d_out;

    const size_t BUF = (size_t)BATCH * T_LEN * P_DIM;
    bf16* qb   = (bf16*)d_ws;
    bf16* kpk  = qb + BUF;       // fragment-packed K
    bf16* vpk  = kpk + BUF;      // fragment-packed V
    bf16* scr  = vpk + BUF;      // scratch region (weights)
    bf16* wkp  = scr;            // packed W_kqv: 196,608 bf16
    bf16* wop  = scr + 262144;   // packed W_out: 65,536 bf16 (disjoint)

    wpack_all_kernel<<<128, 256, 0, stream>>>(W_kqv, W_out, wkp, wop);
    qkv_proj_kernel<<<512, 256, 0, stream>>>(query, wkp, b_kqv, qb, kpk, vpk);
    flash_attn_kernel<<<512, 256, 0, stream>>>(qb, kpk, vpk, wop, b_out, out);
}